// Round 1
// 11037.067 us; speedup vs baseline: 2.5900x; 2.5900x over previous
//
#include <hip/hip_runtime.h>

#define BB 32
#define SS 128
#define HH 1024
#define EE 256
#define VV 16000
#define TT 48
#define VSS (VV + SS)
#define GIN 2304
#define NEGV (-1000000.0f)

__device__ __forceinline__ float dot4(float4 a, float4 b) {
  return a.x * b.x + a.y * b.y + a.z * b.z + a.w * b.w;
}

__device__ __forceinline__ float wave_reduce_sum(float v) {
  for (int o = 32; o; o >>= 1) v += __shfl_down(v, o, 64);
  return v;
}

// ---------------- init: SOS row = 2.0, ids[:,0]=1, sampled=1, sel0=0 ---------------
__global__ __launch_bounds__(256) void k_init(float* __restrict__ out,
                                              float* __restrict__ sel0,
                                              int* __restrict__ samp) {
  const int i = blockIdx.x * 256 + threadIdx.x;
  if (i < BB * VSS) out[i] = 2.0f;
  if (i < BB * HH) sel0[i] = 0.0f;
  if (i < BB) {
    samp[i] = 1;
    out[(size_t)TT * BB * VSS + (size_t)i * TT] = 1.0f;
  }
}

__global__ __launch_bounds__(256) void k_count(const int* __restrict__ inp,
                                               unsigned* __restrict__ mask) {
  const int i = blockIdx.x * 256 + threadIdx.x;
  if (i < BB * SS) {
    const int b = i / SS;
    atomicOr(&mask[inp[i]], 1u << b);
  }
}

// ---------------- th GEMV: th[b][j] = W[j]·h[b] + bias[j] --------------------------
__global__ __launch_bounds__(256) void k_th(const float* __restrict__ W,
                                            const float* __restrict__ bias,
                                            const float* __restrict__ hvec,
                                            float* __restrict__ thout) {
  __shared__ float s_h[HH];
  const int blk = blockIdx.x, tid = threadIdx.x;
  const int b = blk >> 3, bb = blk & 7;
  const int lane = tid & 63, wv = tid >> 6;
  for (int i = tid; i < HH; i += 256) s_h[i] = hvec[b * HH + i];
  __syncthreads();
  const float4* h4 = (const float4*)s_h;
  const int j0 = bb * 128 + wv * 32;
  for (int i = 0; i < 32; ++i) {
    const int j = j0 + i;
    const float4* wr = (const float4*)(W + (size_t)j * HH);
    float acc = 0.f;
#pragma unroll 4
    for (int k = lane; k < HH / 4; k += 64) acc += dot4(wr[k], h4[k]);
    acc = wave_reduce_sum(acc);
    if (lane == 0) thout[b * HH + j] = acc + bias[j];
  }
}

// ---------------- attention part 2: scores, softmax, context -----------------------
// Widened to 512 threads (8 waves on the score loop). All summation orders
// preserved bit-exactly: per-s wave-reduce unchanged; softmax trees padded with
// exact-neutral elements (x+0.0f, fmaxf(x,-inf)); context loop gated to tid<256.
__global__ __launch_bounds__(512) void k_attn2(const float* __restrict__ th,
                                               const float* __restrict__ enc,
                                               float* __restrict__ ctx) {
  __shared__ float s_th[HH];
  __shared__ float s_sc[SS];
  __shared__ float s_red[512];
  const int b = blockIdx.x, tid = threadIdx.x;
  const int lane = tid & 63, wv = tid >> 6;
  for (int i = tid; i < HH; i += 512) s_th[i] = th[b * HH + i];
  __syncthreads();
  const float4* th4 = (const float4*)s_th;
  for (int s = wv; s < SS; s += 8) {
    const float4* er = (const float4*)(enc + ((size_t)b * SS + s) * HH);
    float acc = 0.f;
#pragma unroll 4
    for (int k = lane; k < HH / 4; k += 64) acc += dot4(er[k], th4[k]);
    acc = wave_reduce_sum(acc);
    if (lane == 0) s_sc[s] = acc;
  }
  __syncthreads();
  const float v = (tid < SS) ? s_sc[tid] : -3.4e38f;
  s_red[tid] = v;
  __syncthreads();
  for (int o = 256; o; o >>= 1) {
    if (tid < o) s_red[tid] = fmaxf(s_red[tid], s_red[tid + o]);
    __syncthreads();
  }
  const float m = s_red[0];
  __syncthreads();
  const float e = (tid < SS) ? expf(v - m) : 0.f;
  s_red[tid] = e;
  __syncthreads();
  for (int o = 256; o; o >>= 1) {
    if (tid < o) s_red[tid] += s_red[tid + o];
    __syncthreads();
  }
  const float den = s_red[0];
  __syncthreads();
  if (tid < SS) s_sc[tid] = e / den;
  __syncthreads();
  if (tid < 256) {
    const float4* eb = (const float4*)(enc + (size_t)b * SS * HH);
    float4 acc = make_float4(0.f, 0.f, 0.f, 0.f);
    for (int s = 0; s < SS; ++s) {
      const float a = s_sc[s];
      const float4 x = eb[s * (HH / 4) + tid];
      acc.x += a * x.x; acc.y += a * x.y; acc.z += a * x.z; acc.w += a * x.w;
    }
    ((float4*)(ctx + b * HH))[tid] = acc;
  }
}

// ---------------- GRU chains, batched-broadcast form -------------------------------
// Wave = 2 rows x 32 batches. Weight-row loads are wave-broadcast (lanes 0-31
// share the address), read ONCE per step instead of 32x. x is staged per-k-chunk
// in LDS (stride 130 floats -> 2-way bank aliasing = free; float2 reads keep it
// conflict-free; lanes 32-63 broadcast lanes 0-31's addresses).
// Per-output accumulation order is bit-identical to round-2's k_gru2:
// sequential float4 k over [ctx | sel | emb] (ih) or h (hh), bias added last.
__global__ __launch_bounds__(256) void k_gru3(const float* __restrict__ hc,
                                              const float* __restrict__ ctx,
                                              const float* __restrict__ sel,
                                              const float* __restrict__ embt,
                                              const int* __restrict__ samp,
                                              const float* __restrict__ Wih,
                                              const float* __restrict__ Whh,
                                              const float* __restrict__ bih,
                                              const float* __restrict__ bhh,
                                              float* __restrict__ gbuf) {
  __shared__ float s_x[32][130];
  const int blk = blockIdx.x, tid = threadIdx.x;
  const int lane = tid & 63, wv = tid >> 6;
  const int b = lane & 31, rp = lane >> 5;
  const int lb = tid >> 3, lg = tid & 7;
  const bool ih = blk < 384;
  const int base = (ih ? blk : blk - 384) * 8;
  const int row = base + 2 * wv + rp;  // 0..3071
  float acc = 0.f;
  int ei = 0;
  if (ih) {
    const int p = samp[lb];
    ei = (p > VV) ? 3 : p;       // strict >, as in source
    if (ei >= VV) ei = VV - 1;   // jnp OOB gather clamps
  }
  const int NCH = ih ? 18 : 8;
  for (int ch = 0; ch < NCH; ++ch) {
    // cooperative load of x chunk: 32 b x 128 floats (coalesced float4 reads)
    const float* src;
    if (ih) {
      if (ch < 8) src = ctx + lb * HH + ch * 128;
      else if (ch < 16) src = sel + lb * HH + (ch - 8) * 128;
      else src = embt + (size_t)ei * EE + (ch - 16) * 128;
    } else {
      src = hc + lb * HH + ch * 128;
    }
    float2* drow = (float2*)&s_x[lb][0];
#pragma unroll
    for (int m = 0; m < 4; ++m) {
      const int col = lg + m * 8;
      const float4 v4 = ((const float4*)src)[col];
      drow[2 * col] = make_float2(v4.x, v4.y);
      drow[2 * col + 1] = make_float2(v4.z, v4.w);
    }
    __syncthreads();
    const float4* wr = ih ? (const float4*)(Wih + (size_t)row * GIN + ch * 128)
                          : (const float4*)(Whh + (size_t)row * HH + ch * 128);
    const float2* xr = (const float2*)&s_x[b][0];
#pragma unroll 8
    for (int kc = 0; kc < 32; ++kc) {
      const float2 xa = xr[2 * kc], xb2 = xr[2 * kc + 1];
      acc += dot4(wr[kc], make_float4(xa.x, xa.y, xb2.x, xb2.y));
    }
    __syncthreads();
  }
  if (ih) {
    acc += bih[row];
    gbuf[(size_t)(row >> 10) * (BB * HH) + b * HH + (row & 1023)] = acc;
  } else {
    acc += bhh[row];
    gbuf[(size_t)(3 + (row >> 10)) * (BB * HH) + b * HH + (row & 1023)] = acc;
  }
}

__global__ __launch_bounds__(256) void k_grufin(const float* __restrict__ gbuf,
                                                const float* __restrict__ hc,
                                                float* __restrict__ hn) {
  const int gid = blockIdx.x * 256 + threadIdx.x;
  const int b = gid >> 10, j = gid & 1023;
  const int o = b * HH + j;
  const float gxr = gbuf[0 * (BB * HH) + o];
  const float gxz = gbuf[1 * (BB * HH) + o];
  const float gxn = gbuf[2 * (BB * HH) + o];
  const float ghr = gbuf[3 * (BB * HH) + o];
  const float ghz = gbuf[4 * (BB * HH) + o];
  const float ghn = gbuf[5 * (BB * HH) + o];
  const float rr = 1.f / (1.f + expf(-(gxr + ghr)));
  const float zz = 1.f / (1.f + expf(-(gxz + ghz)));
  const float nn = tanhf(gxn + rr * ghn);
  hn[o] = (1.f - zz) * nn + zz * hc[o];
}

// ---------------- copy part 2: cseq = enc.th2 ; zero + scatter ---------------------
// Widened to 512 threads; per-s wave-reduce order unchanged (bit-exact).
__global__ __launch_bounds__(512) void k_copy2(const float* __restrict__ th2,
                                               const float* __restrict__ enc,
                                               const int* __restrict__ inp,
                                               float* __restrict__ cseq,
                                               float* __restrict__ cvals) {
  __shared__ float s_th[HH];
  __shared__ float s_sc[SS];
  const int b = blockIdx.x, tid = threadIdx.x;
  const int lane = tid & 63, wv = tid >> 6;
  for (int i = tid; i < HH; i += 512) s_th[i] = th2[b * HH + i];
  __syncthreads();
  const float4* th4 = (const float4*)s_th;
  for (int s = wv; s < SS; s += 8) {
    const float4* er = (const float4*)(enc + ((size_t)b * SS + s) * HH);
    float acc = 0.f;
#pragma unroll 4
    for (int k = lane; k < HH / 4; k += 64) acc += dot4(er[k], th4[k]);
    acc = wave_reduce_sum(acc);
    if (lane == 0) {
      s_sc[s] = acc;
      cseq[b * SS + s] = acc;
    }
  }
  for (int i = tid; i < VV; i += 512) cvals[(size_t)b * VV + i] = 0.f;
  __syncthreads();
  if (tid < SS) atomicAdd(&cvals[(size_t)b * VV + inp[b * SS + tid]], s_sc[tid]);
}

// ---------------- generate logits, batched-broadcast form --------------------------
// Block = 16 v-rows x 32 b; wave = 2 rows x 32 b with 2 row-pairs (2 accs/lane).
// Wo rows wave-broadcast; h staged per-k-chunk in LDS. Accumulation order per
// (b,v) is bit-identical to round-2's k_gen (sequential float4 k, bias last).
__global__ __launch_bounds__(256) void k_gen3(const float* __restrict__ hn,
                                              const float* __restrict__ Wo,
                                              const float* __restrict__ bo,
                                              float* __restrict__ gen) {
  __shared__ float s_h[32][130];
  const int blk = blockIdx.x, tid = threadIdx.x;
  const int lane = tid & 63, wv = tid >> 6;
  const int b = lane & 31, rp = lane >> 5;
  const int lb = tid >> 3, lg = tid & 7;
  const int v0 = blk * 16;
  const int va = v0 + 2 * wv + rp;
  const int vb = va + 8;
  float acc0 = 0.f, acc1 = 0.f;
  for (int ch = 0; ch < 8; ++ch) {
    const float* src = hn + lb * HH + ch * 128;
    float2* drow = (float2*)&s_h[lb][0];
#pragma unroll
    for (int m = 0; m < 4; ++m) {
      const int col = lg + m * 8;
      const float4 v4 = ((const float4*)src)[col];
      drow[2 * col] = make_float2(v4.x, v4.y);
      drow[2 * col + 1] = make_float2(v4.z, v4.w);
    }
    __syncthreads();
    const float4* wr0 = (const float4*)(Wo + (size_t)va * HH + ch * 128);
    const float4* wr1 = (const float4*)(Wo + (size_t)vb * HH + ch * 128);
    const float2* xr = (const float2*)&s_h[b][0];
#pragma unroll 8
    for (int kc = 0; kc < 32; ++kc) {
      const float2 xa = xr[2 * kc], xb2 = xr[2 * kc + 1];
      const float4 xv = make_float4(xa.x, xa.y, xb2.x, xb2.y);
      acc0 += dot4(wr0[kc], xv);
      acc1 += dot4(wr1[kc], xv);
    }
    __syncthreads();
  }
  gen[(size_t)b * VV + va] = acc0 + bo[va];
  gen[(size_t)b * VV + vb] = acc1 + bo[vb];
}

// ---------------- softmax/log/argmax/sel-read --------------------------------------
// Widened to 1024 threads (4 waves/SIMD: V-pass trip count 63 -> 16).
// Argmax unaffected: max is order-independent; the denominator is a common
// factor across all slots so ordering of lp is preserved. sel-read summation
// kept bit-exact (old 256-thread loop gated; abs-sum tree pads exact zeros).
__global__ __launch_bounds__(1024) void k_out(const float* __restrict__ gen,
                                              const float* __restrict__ cvals,
                                              const unsigned* __restrict__ mask,
                                              const float* __restrict__ cseq,
                                              const int* __restrict__ inp,
                                              const float* __restrict__ enc,
                                              float* __restrict__ out,
                                              float* __restrict__ seln,
                                              int* __restrict__ samp,
                                              const int t) {
  __shared__ float s_red[1024];
  __shared__ int s_idx[1024];
  __shared__ float s_norm[SS];
  const int b = blockIdx.x, tid = threadIdx.x;
  const float* gb = gen + (size_t)b * VV;
  const float* cb = cvals + (size_t)b * VV;
  // pass 1: max over all logits (extended slots are NEGV, never the max)
  float m = -3.4e38f;
  for (int v = tid; v < VV; v += 1024) {
    const float gv = (v == 0) ? NEGV : gb[v];
    const float cv = (v == 0 || !((mask[v] >> b) & 1u)) ? NEGV : cb[v];
    m = fmaxf(m, fmaxf(gv, cv));
  }
  s_red[tid] = m;
  __syncthreads();
  for (int o = 512; o; o >>= 1) {
    if (tid < o) s_red[tid] = fmaxf(s_red[tid], s_red[tid + o]);
    __syncthreads();
  }
  m = s_red[0];
  __syncthreads();
  // pass 2: denominator (NEGV slots contribute exactly 0 in fp32)
  float sm = 0.f;
  for (int v = tid; v < VV; v += 1024) {
    const float gv = (v == 0) ? NEGV : gb[v];
    const float cv = (v == 0 || !((mask[v] >> b) & 1u)) ? NEGV : cb[v];
    sm += expf(gv - m) + expf(cv - m);
  }
  s_red[tid] = sm;
  __syncthreads();
  for (int o = 512; o; o >>= 1) {
    if (tid < o) s_red[tid] += s_red[tid + o];
    __syncthreads();
  }
  const float inv = 1.f / s_red[0];
  __syncthreads();
  // pass 3: probs -> log -> write + argmax (first-index tie-break)
  float bv = -3.4e38f;
  int bi = VSS;
  float* ob = out + ((size_t)t * BB + b) * VSS;
  for (int v = tid; v < VV; v += 1024) {
    const float gv = (v == 0) ? NEGV : gb[v];
    const float cv = (v == 0 || !((mask[v] >> b) & 1u)) ? NEGV : cb[v];
    const float p = expf(gv - m) * inv + expf(cv - m) * inv;
    const float lp = logf(p + 1e-10f);
    ob[v] = lp;
    if (lp > bv) { bv = lp; bi = v; }
  }
  const float lpz = logf(1e-10f);  // extended-vocab slots: prob exactly 0
  for (int j = VV + tid; j < VSS; j += 1024) ob[j] = lpz;
  s_red[tid] = bv;
  s_idx[tid] = bi;
  __syncthreads();
  for (int o = 512; o; o >>= 1) {
    if (tid < o) {
      const float ov = s_red[tid + o];
      const int oi = s_idx[tid + o];
      if (ov > s_red[tid] || (ov == s_red[tid] && oi < s_idx[tid])) {
        s_red[tid] = ov;
        s_idx[tid] = oi;
      }
    }
    __syncthreads();
  }
  const int sp = s_idx[0];
  if (tid == 0) {
    samp[b] = sp;
    out[(size_t)TT * BB * VSS + (size_t)b * TT + t] = (float)sp;
  }
  __syncthreads();
  // selective read: selected = (inp==sp)*cseq ; norm ; sel_new = norm @ enc
  float sv = 0.f;
  if (tid < SS) sv = (inp[b * SS + tid] == sp) ? cseq[b * SS + tid] : 0.f;
  s_red[tid] = (tid < SS) ? fabsf(sv) : 0.f;
  __syncthreads();
  for (int o = 512; o; o >>= 1) {
    if (tid < o) s_red[tid] += s_red[tid + o];
    __syncthreads();
  }
  const float nf = 1.f / fmaxf(s_red[0], 1e-12f);
  __syncthreads();
  if (tid < SS) s_norm[tid] = sv * nf;
  __syncthreads();
  if (tid < 256) {
    const float4* eb = (const float4*)(enc + (size_t)b * SS * HH);
    float4 acc = make_float4(0.f, 0.f, 0.f, 0.f);
    for (int s = 0; s < SS; ++s) {
      const float a = s_norm[s];
      if (a != 0.f) {
        const float4 x = eb[s * (HH / 4) + tid];
        acc.x += a * x.x; acc.y += a * x.y; acc.z += a * x.z; acc.w += a * x.w;
      }
    }
    ((float4*)(seln + b * HH))[tid] = acc;
  }
}

extern "C" void kernel_launch(void* const* d_in, const int* in_sizes, int n_in,
                              void* d_out, int out_size, void* d_ws, size_t ws_size,
                              hipStream_t stream) {
  const int* inp = (const int*)d_in[0];
  const float* hidden = (const float*)d_in[1];
  const float* enc = (const float*)d_in[2];
  const float* Wa = (const float*)d_in[4];
  const float* ba = (const float*)d_in[5];
  const float* Wc = (const float*)d_in[6];
  const float* bc = (const float*)d_in[7];
  const float* emb = (const float*)d_in[8];
  const float* Wih = (const float*)d_in[9];
  const float* Whh = (const float*)d_in[10];
  const float* bih = (const float*)d_in[11];
  const float* bhh = (const float*)d_in[12];
  const float* Wo = (const float*)d_in[13];
  const float* bo = (const float*)d_in[14];
  float* out = (float*)d_out;

  float* ws = (float*)d_ws;
  float* hb0 = ws;                        // [B*H]
  float* hb1 = hb0 + BB * HH;             // [B*H]
  float* sb0 = hb1 + BB * HH;             // [B*H]
  float* sb1 = sb0 + BB * HH;             // [B*H]
  float* ctx = sb1 + BB * HH;             // [B*H]
  float* th = ctx + BB * HH;              // [B*H]
  float* th2 = th + BB * HH;              // [B*H]
  float* gbuf = th2 + BB * HH;            // [6*B*H]
  float* cseq = gbuf + 6 * BB * HH;       // [B*S]
  float* gen = cseq + BB * SS;            // [B*V]
  float* cvals = gen + (size_t)BB * VV;   // [B*V]
  unsigned* mask = (unsigned*)(cvals + (size_t)BB * VV);  // [V]
  int* samp = (int*)(mask + VV);          // [B]

  hipMemsetAsync(mask, 0, (size_t)VV * 4, stream);
  k_init<<<(BB * VSS + 255) / 256, 256, 0, stream>>>(out, sb0, samp);
  k_count<<<(BB * SS + 255) / 256, 256, 0, stream>>>(inp, mask);

  for (int t = 1; t < TT; ++t) {
    const float* hc = (t == 1) ? hidden : (((t - 1) & 1) ? hb0 : hb1);
    float* hw = (t & 1) ? hb0 : hb1;
    const float* sr = (t == 1) ? sb0 : (((t - 1) & 1) ? sb1 : sb0);
    float* sw = (t & 1) ? sb1 : sb0;

    k_th<<<BB * 8, 256, 0, stream>>>(Wa, ba, hc, th);
    k_attn2<<<BB, 512, 0, stream>>>(th, enc, ctx);
    k_gru3<<<768, 256, 0, stream>>>(hc, ctx, sr, emb, samp, Wih, Whh, bih, bhh,
                                    gbuf);
    k_grufin<<<BB * HH / 256, 256, 0, stream>>>(gbuf, hc, hw);
    k_th<<<BB * 8, 256, 0, stream>>>(Wc, bc, hw, th2);
    k_copy2<<<BB, 512, 0, stream>>>(th2, enc, inp, cseq, cvals);
    k_gen3<<<VV / 16, 256, 0, stream>>>(hw, Wo, bo, gen);
    k_out<<<BB, 1024, 0, stream>>>(gen, cvals, mask, cseq, inp, enc, out, sw, samp,
                                   t);
  }
}

// Round 5
// 10474.522 us; speedup vs baseline: 2.7291x; 1.0537x over previous
//
#include <hip/hip_runtime.h>

#define BB 32
#define SS 128
#define HH 1024
#define EE 256
#define VV 16000
#define TT 48
#define VSS (VV + SS)
#define GIN 2304
#define NEGV (-1000000.0f)

__device__ __forceinline__ float dot4(float4 a, float4 b) {
  return a.x * b.x + a.y * b.y + a.z * b.z + a.w * b.w;
}

__device__ __forceinline__ float wave_reduce_sum(float v) {
  for (int o = 32; o; o >>= 1) v += __shfl_down(v, o, 64);
  return v;
}

// ---------------- init: SOS row = 2.0, ids[:,0]=1, sampled=1, sel0=0 ---------------
__global__ __launch_bounds__(256) void k_init(float* __restrict__ out,
                                              float* __restrict__ sel0,
                                              int* __restrict__ samp) {
  const int i = blockIdx.x * 256 + threadIdx.x;
  if (i < BB * VSS) out[i] = 2.0f;
  if (i < BB * HH) sel0[i] = 0.0f;
  if (i < BB) {
    samp[i] = 1;
    out[(size_t)TT * BB * VSS + (size_t)i * TT] = 1.0f;
  }
}

// ---------------- th GEMV (round-1 verbatim, passed @11.0ms) -----------------------
__global__ __launch_bounds__(256) void k_th(const float* __restrict__ W,
                                            const float* __restrict__ bias,
                                            const float* __restrict__ hvec,
                                            float* __restrict__ thout) {
  __shared__ float s_h[HH];
  const int blk = blockIdx.x, tid = threadIdx.x;
  const int b = blk >> 3, bb = blk & 7;
  const int lane = tid & 63, wv = tid >> 6;
  for (int i = tid; i < HH; i += 256) s_h[i] = hvec[b * HH + i];
  __syncthreads();
  const float4* h4 = (const float4*)s_h;
  const int j0 = bb * 128 + wv * 32;
  for (int i = 0; i < 32; ++i) {
    const int j = j0 + i;
    const float4* wr = (const float4*)(W + (size_t)j * HH);
    float acc = 0.f;
#pragma unroll 4
    for (int k = lane; k < HH / 4; k += 64) acc += dot4(wr[k], h4[k]);
    acc = wave_reduce_sum(acc);
    if (lane == 0) thout[b * HH + j] = acc + bias[j];
  }
}

// ---------------- attention part 2 (round-1 verbatim, passed @11.0ms) --------------
__global__ __launch_bounds__(512) void k_attn2(const float* __restrict__ th,
                                               const float* __restrict__ enc,
                                               float* __restrict__ ctx) {
  __shared__ float s_th[HH];
  __shared__ float s_sc[SS];
  __shared__ float s_red[512];
  const int b = blockIdx.x, tid = threadIdx.x;
  const int lane = tid & 63, wv = tid >> 6;
  for (int i = tid; i < HH; i += 512) s_th[i] = th[b * HH + i];
  __syncthreads();
  const float4* th4 = (const float4*)s_th;
  for (int s = wv; s < SS; s += 8) {
    const float4* er = (const float4*)(enc + ((size_t)b * SS + s) * HH);
    float acc = 0.f;
#pragma unroll 4
    for (int k = lane; k < HH / 4; k += 64) acc += dot4(er[k], th4[k]);
    acc = wave_reduce_sum(acc);
    if (lane == 0) s_sc[s] = acc;
  }
  __syncthreads();
  const float v = (tid < SS) ? s_sc[tid] : -3.4e38f;
  s_red[tid] = v;
  __syncthreads();
  for (int o = 256; o; o >>= 1) {
    if (tid < o) s_red[tid] = fmaxf(s_red[tid], s_red[tid + o]);
    __syncthreads();
  }
  const float m = s_red[0];
  __syncthreads();
  const float e = (tid < SS) ? expf(v - m) : 0.f;
  s_red[tid] = e;
  __syncthreads();
  for (int o = 256; o; o >>= 1) {
    if (tid < o) s_red[tid] += s_red[tid + o];
    __syncthreads();
  }
  const float den = s_red[0];
  __syncthreads();
  if (tid < SS) s_sc[tid] = e / den;
  __syncthreads();
  if (tid < 256) {
    const float4* eb = (const float4*)(enc + (size_t)b * SS * HH);
    float4 acc = make_float4(0.f, 0.f, 0.f, 0.f);
    for (int s = 0; s < SS; ++s) {
      const float a = s_sc[s];
      const float4 x = eb[s * (HH / 4) + tid];
      acc.x += a * x.x; acc.y += a * x.y; acc.z += a * x.z; acc.w += a * x.w;
    }
    ((float4*)(ctx + b * HH))[tid] = acc;
  }
}

// ---------------- GRU chains (round-1 verbatim k_gru3, passed @11.0ms) -------------
__global__ __launch_bounds__(256) void k_gru3(const float* __restrict__ hc,
                                              const float* __restrict__ ctx,
                                              const float* __restrict__ sel,
                                              const float* __restrict__ embt,
                                              const int* __restrict__ samp,
                                              const float* __restrict__ Wih,
                                              const float* __restrict__ Whh,
                                              const float* __restrict__ bih,
                                              const float* __restrict__ bhh,
                                              float* __restrict__ gbuf) {
  __shared__ float s_x[32][130];
  const int blk = blockIdx.x, tid = threadIdx.x;
  const int lane = tid & 63, wv = tid >> 6;
  const int b = lane & 31, rp = lane >> 5;
  const int lb = tid >> 3, lg = tid & 7;
  const bool ih = blk < 384;
  const int base = (ih ? blk : blk - 384) * 8;
  const int row = base + 2 * wv + rp;  // 0..3071
  float acc = 0.f;
  int ei = 0;
  if (ih) {
    const int p = samp[lb];
    ei = (p > VV) ? 3 : p;       // strict >, as in source
    if (ei >= VV) ei = VV - 1;   // jnp OOB gather clamps
  }
  const int NCH = ih ? 18 : 8;
  for (int ch = 0; ch < NCH; ++ch) {
    const float* src;
    if (ih) {
      if (ch < 8) src = ctx + lb * HH + ch * 128;
      else if (ch < 16) src = sel + lb * HH + (ch - 8) * 128;
      else src = embt + (size_t)ei * EE + (ch - 16) * 128;
    } else {
      src = hc + lb * HH + ch * 128;
    }
    float2* drow = (float2*)&s_x[lb][0];
#pragma unroll
    for (int m = 0; m < 4; ++m) {
      const int col = lg + m * 8;
      const float4 v4 = ((const float4*)src)[col];
      drow[2 * col] = make_float2(v4.x, v4.y);
      drow[2 * col + 1] = make_float2(v4.z, v4.w);
    }
    __syncthreads();
    const float4* wr = ih ? (const float4*)(Wih + (size_t)row * GIN + ch * 128)
                          : (const float4*)(Whh + (size_t)row * HH + ch * 128);
    const float2* xr = (const float2*)&s_x[b][0];
#pragma unroll 8
    for (int kc = 0; kc < 32; ++kc) {
      const float2 xa = xr[2 * kc], xb2 = xr[2 * kc + 1];
      acc += dot4(wr[kc], make_float4(xa.x, xa.y, xb2.x, xb2.y));
    }
    __syncthreads();
  }
  if (ih) {
    acc += bih[row];
    gbuf[(size_t)(row >> 10) * (BB * HH) + b * HH + (row & 1023)] = acc;
  } else {
    acc += bhh[row];
    gbuf[(size_t)(3 + (row >> 10)) * (BB * HH) + b * HH + (row & 1023)] = acc;
  }
}

__global__ __launch_bounds__(256) void k_grufin(const float* __restrict__ gbuf,
                                                const float* __restrict__ hc,
                                                float* __restrict__ hn) {
  const int gid = blockIdx.x * 256 + threadIdx.x;
  const int b = gid >> 10, j = gid & 1023;
  const int o = b * HH + j;
  const float gxr = gbuf[0 * (BB * HH) + o];
  const float gxz = gbuf[1 * (BB * HH) + o];
  const float gxn = gbuf[2 * (BB * HH) + o];
  const float ghr = gbuf[3 * (BB * HH) + o];
  const float ghz = gbuf[4 * (BB * HH) + o];
  const float ghn = gbuf[5 * (BB * HH) + o];
  const float rr = 1.f / (1.f + expf(-(gxr + ghr)));
  const float zz = 1.f / (1.f + expf(-(gxz + ghz)));
  const float nn = tanhf(gxn + rr * ghn);
  hn[o] = (1.f - zz) * nn + zz * hc[o];
}

// ---------------- generate logits (round-1 verbatim k_gen3, passed @11.0ms) --------
__global__ __launch_bounds__(256) void k_gen3(const float* __restrict__ hn,
                                              const float* __restrict__ Wo,
                                              const float* __restrict__ bo,
                                              float* __restrict__ gen) {
  __shared__ float s_h[32][130];
  const int blk = blockIdx.x, tid = threadIdx.x;
  const int lane = tid & 63, wv = tid >> 6;
  const int b = lane & 31, rp = lane >> 5;
  const int lb = tid >> 3, lg = tid & 7;
  const int v0 = blk * 16;
  const int va = v0 + 2 * wv + rp;
  const int vb = va + 8;
  float acc0 = 0.f, acc1 = 0.f;
  for (int ch = 0; ch < 8; ++ch) {
    const float* src = hn + lb * HH + ch * 128;
    float2* drow = (float2*)&s_h[lb][0];
#pragma unroll
    for (int m = 0; m < 4; ++m) {
      const int col = lg + m * 8;
      const float4 v4 = ((const float4*)src)[col];
      drow[2 * col] = make_float2(v4.x, v4.y);
      drow[2 * col + 1] = make_float2(v4.z, v4.w);
    }
    __syncthreads();
    const float4* wr0 = (const float4*)(Wo + (size_t)va * HH + ch * 128);
    const float4* wr1 = (const float4*)(Wo + (size_t)vb * HH + ch * 128);
    const float2* xr = (const float2*)&s_h[b][0];
#pragma unroll 8
    for (int kc = 0; kc < 32; ++kc) {
      const float2 xa = xr[2 * kc], xb2 = xr[2 * kc + 1];
      const float4 xv = make_float4(xa.x, xa.y, xb2.x, xb2.y);
      acc0 += dot4(wr0[kc], xv);
      acc1 += dot4(wr1[kc], xv);
    }
    __syncthreads();
  }
  gen[(size_t)b * VV + va] = acc0 + bo[va];
  gen[(size_t)b * VV + vb] = acc1 + bo[vb];
}

// ---------------- fused copy2 + out, hash-table edition (suspect under test) -------
// Copy scores live in a 512-entry LDS hash over batch b's <=128 source tokens:
// presence-in-hash == old mask bit; value == old cvals scatter sum. Per-v logit
// values, pass structure, reduction trees, tie-break, selective read: verbatim
// round-1 1024-thread k_out; gen/copy logits register-cached across the 3 passes.
__global__ __launch_bounds__(1024) void k_fin(const float* __restrict__ th2,
                                              const float* __restrict__ enc,
                                              const int* __restrict__ inp,
                                              const float* __restrict__ gen,
                                              float* __restrict__ out,
                                              float* __restrict__ seln,
                                              int* __restrict__ samp,
                                              const int t) {
  __shared__ float s_th[HH];
  __shared__ float s_red[1024];
  __shared__ int s_idx[1024];
  __shared__ float s_sc[SS];
  __shared__ float s_norm[SS];
  __shared__ int hkey[512];
  __shared__ float hval[512];
  const int b = blockIdx.x, tid = threadIdx.x;
  const int lane = tid & 63, wv = tid >> 6;  // 16 waves
  // ---- part A: copy scores (bit-exact k_copy2 per-s math) + hash scatter ----
  for (int i = tid; i < HH; i += 1024) s_th[i] = th2[b * HH + i];
  if (tid < 512) { hkey[tid] = -1; hval[tid] = 0.f; }
  __syncthreads();
  const float4* th4 = (const float4*)s_th;
  for (int s = wv; s < SS; s += 16) {
    const float4* er = (const float4*)(enc + ((size_t)b * SS + s) * HH);
    float acc = 0.f;
#pragma unroll 4
    for (int k = lane; k < HH / 4; k += 64) acc += dot4(er[k], th4[k]);
    acc = wave_reduce_sum(acc);
    if (lane == 0) s_sc[s] = acc;
  }
  __syncthreads();
  if (tid < SS) {
    const int tok = inp[b * SS + tid];
    const float val = s_sc[tid];
    unsigned h = ((unsigned)tok * 2654435761u) >> 23;  // 9 bits -> 0..511
    while (true) {
      const int prev = atomicCAS(&hkey[h], -1, tok);
      if (prev == -1 || prev == tok) { atomicAdd(&hval[h], val); break; }
      h = (h + 1) & 511;
    }
  }
  __syncthreads();
  // ---- part B: softmax/log/argmax (register-cached logits) ----
  const float* gb = gen + (size_t)b * VV;
  float gr[16], cr[16];
  float m = -3.4e38f;
#pragma unroll
  for (int k = 0; k < 16; ++k) {
    const int v = tid + k * 1024;
    if (v < VV) {
      const float gv = (v == 0) ? NEGV : gb[v];
      float cv = NEGV;
      if (v != 0) {
        unsigned h = ((unsigned)v * 2654435761u) >> 23;
        while (true) {
          const int kk = hkey[h];
          if (kk == v) { cv = hval[h]; break; }
          if (kk == -1) break;
          h = (h + 1) & 511;
        }
      }
      gr[k] = gv; cr[k] = cv;
      m = fmaxf(m, fmaxf(gv, cv));
    }
  }
  s_red[tid] = m;
  __syncthreads();
  for (int o = 512; o; o >>= 1) {
    if (tid < o) s_red[tid] = fmaxf(s_red[tid], s_red[tid + o]);
    __syncthreads();
  }
  m = s_red[0];
  __syncthreads();
  float sm = 0.f;
#pragma unroll
  for (int k = 0; k < 16; ++k) {
    const int v = tid + k * 1024;
    if (v < VV) sm += expf(gr[k] - m) + expf(cr[k] - m);
  }
  s_red[tid] = sm;
  __syncthreads();
  for (int o = 512; o; o >>= 1) {
    if (tid < o) s_red[tid] += s_red[tid + o];
    __syncthreads();
  }
  const float inv = 1.f / s_red[0];
  __syncthreads();
  float bv = -3.4e38f;
  int bi = VSS;
  float* ob = out + ((size_t)t * BB + b) * VSS;
#pragma unroll
  for (int k = 0; k < 16; ++k) {
    const int v = tid + k * 1024;
    if (v < VV) {
      const float p = expf(gr[k] - m) * inv + expf(cr[k] - m) * inv;
      const float lp = logf(p + 1e-10f);
      ob[v] = lp;
      if (lp > bv) { bv = lp; bi = v; }
    }
  }
  const float lpz = logf(1e-10f);  // extended-vocab slots: prob exactly 0
  for (int j = VV + tid; j < VSS; j += 1024) ob[j] = lpz;
  s_red[tid] = bv;
  s_idx[tid] = bi;
  __syncthreads();
  for (int o = 512; o; o >>= 1) {
    if (tid < o) {
      const float ov = s_red[tid + o];
      const int oi = s_idx[tid + o];
      if (ov > s_red[tid] || (ov == s_red[tid] && oi < s_idx[tid])) {
        s_red[tid] = ov;
        s_idx[tid] = oi;
      }
    }
    __syncthreads();
  }
  const int sp = s_idx[0];
  if (tid == 0) {
    samp[b] = sp;
    out[(size_t)TT * BB * VSS + (size_t)b * TT + t] = (float)sp;
  }
  __syncthreads();
  // ---- selective read (cseq values = s_sc, identical) ----
  float sv = 0.f;
  if (tid < SS) sv = (inp[b * SS + tid] == sp) ? s_sc[tid] : 0.f;
  s_red[tid] = (tid < SS) ? fabsf(sv) : 0.f;
  __syncthreads();
  for (int o = 512; o; o >>= 1) {
    if (tid < o) s_red[tid] += s_red[tid + o];
    __syncthreads();
  }
  const float nf = 1.f / fmaxf(s_red[0], 1e-12f);
  __syncthreads();
  if (tid < SS) s_norm[tid] = sv * nf;
  __syncthreads();
  if (tid < 256) {
    const float4* eb = (const float4*)(enc + (size_t)b * SS * HH);
    float4 acc = make_float4(0.f, 0.f, 0.f, 0.f);
    for (int s = 0; s < SS; ++s) {
      const float a = s_norm[s];
      if (a != 0.f) {
        const float4 x = eb[s * (HH / 4) + tid];
        acc.x += a * x.x; acc.y += a * x.y; acc.z += a * x.z; acc.w += a * x.w;
      }
    }
    ((float4*)(seln + b * HH))[tid] = acc;
  }
}

extern "C" void kernel_launch(void* const* d_in, const int* in_sizes, int n_in,
                              void* d_out, int out_size, void* d_ws, size_t ws_size,
                              hipStream_t stream) {
  const int* inp = (const int*)d_in[0];
  const float* hidden = (const float*)d_in[1];
  const float* enc = (const float*)d_in[2];
  const float* Wa = (const float*)d_in[4];
  const float* ba = (const float*)d_in[5];
  const float* Wc = (const float*)d_in[6];
  const float* bc = (const float*)d_in[7];
  const float* emb = (const float*)d_in[8];
  const float* Wih = (const float*)d_in[9];
  const float* Whh = (const float*)d_in[10];
  const float* bih = (const float*)d_in[11];
  const float* bhh = (const float*)d_in[12];
  const float* Wo = (const float*)d_in[13];
  const float* bo = (const float*)d_in[14];
  float* out = (float*)d_out;

  float* ws = (float*)d_ws;
  float* hb0 = ws;                        // [B*H]
  float* hb1 = hb0 + BB * HH;             // [B*H]
  float* sb0 = hb1 + BB * HH;             // [B*H]
  float* sb1 = sb0 + BB * HH;             // [B*H]
  float* ctx = sb1 + BB * HH;             // [B*H]
  float* th = ctx + BB * HH;              // [B*H]
  float* th2 = th + BB * HH;              // [B*H]
  float* gbuf = th2 + BB * HH;            // [6*B*H]
  float* gen = gbuf + 6 * BB * HH;        // [B*V]
  int* samp = (int*)(gen + (size_t)BB * VV);  // [B]

  k_init<<<(BB * VSS + 255) / 256, 256, 0, stream>>>(out, sb0, samp);

  for (int t = 1; t < TT; ++t) {
    const float* hc = (t == 1) ? hidden : (((t - 1) & 1) ? hb0 : hb1);
    float* hw = (t & 1) ? hb0 : hb1;
    const float* sr = (t == 1) ? sb0 : (((t - 1) & 1) ? sb1 : sb0);
    float* sw = (t & 1) ? sb1 : sb0;

    k_th<<<BB * 8, 256, 0, stream>>>(Wa, ba, hc, th);
    k_attn2<<<BB, 512, 0, stream>>>(th, enc, ctx);
    k_gru3<<<768, 256, 0, stream>>>(hc, ctx, sr, emb, samp, Wih, Whh, bih, bhh,
                                    gbuf);
    k_grufin<<<BB * HH / 256, 256, 0, stream>>>(gbuf, hc, hw);
    k_th<<<BB * 8, 256, 0, stream>>>(Wc, bc, hw, th2);
    k_gen3<<<VV / 16, 256, 0, stream>>>(hw, Wo, bo, gen);
    k_fin<<<BB, 1024, 0, stream>>>(th2, enc, inp, gen, out, sw, samp, t);
  }
}

// Round 8
// 10439.449 us; speedup vs baseline: 2.7382x; 1.0034x over previous
//
#include <hip/hip_runtime.h>

#define BB 32
#define SS 128
#define HH 1024
#define EE 256
#define VV 16000
#define TT 48
#define VSS (VV + SS)
#define GIN 2304
#define NEGV (-1000000.0f)

__device__ __forceinline__ float dot4(float4 a, float4 b) {
  return a.x * b.x + a.y * b.y + a.z * b.z + a.w * b.w;
}

__device__ __forceinline__ float wave_reduce_sum(float v) {
  for (int o = 32; o; o >>= 1) v += __shfl_down(v, o, 64);
  return v;
}

// ---------------- init: SOS row = 2.0, ids[:,0]=1, sampled=1, sel0=0 ---------------
__global__ __launch_bounds__(256) void k_init(float* __restrict__ out,
                                              float* __restrict__ sel0,
                                              int* __restrict__ samp) {
  const int i = blockIdx.x * 256 + threadIdx.x;
  if (i < BB * VSS) out[i] = 2.0f;
  if (i < BB * HH) sel0[i] = 0.0f;
  if (i < BB) {
    samp[i] = 1;
    out[(size_t)TT * BB * VSS + (size_t)i * TT] = 1.0f;
  }
}

// ---------------- th GEMV (round-1 verbatim, passing) ------------------------------
__global__ __launch_bounds__(256) void k_th(const float* __restrict__ W,
                                            const float* __restrict__ bias,
                                            const float* __restrict__ hvec,
                                            float* __restrict__ thout) {
  __shared__ float s_h[HH];
  const int blk = blockIdx.x, tid = threadIdx.x;
  const int b = blk >> 3, bb = blk & 7;
  const int lane = tid & 63, wv = tid >> 6;
  for (int i = tid; i < HH; i += 256) s_h[i] = hvec[b * HH + i];
  __syncthreads();
  const float4* h4 = (const float4*)s_h;
  const int j0 = bb * 128 + wv * 32;
  for (int i = 0; i < 32; ++i) {
    const int j = j0 + i;
    const float4* wr = (const float4*)(W + (size_t)j * HH);
    float acc = 0.f;
#pragma unroll 4
    for (int k = lane; k < HH / 4; k += 64) acc += dot4(wr[k], h4[k]);
    acc = wave_reduce_sum(acc);
    if (lane == 0) thout[b * HH + j] = acc + bias[j];
  }
}

// ---------------- fused grufin + th GEMV -------------------------------------------
// Prologue computes hn[b][*] from gbuf/hc with the EXACT grufin expression (same
// per-element order -> bit-identical values), into s_h directly; the bb==0 sibling
// block also writes hn to global (for k_gen3 and the next step). Body below the
// barrier is the round-1 k_th body verbatim.
__global__ __launch_bounds__(256) void k_thg(const float* __restrict__ W,
                                             const float* __restrict__ bias,
                                             const float* __restrict__ gbuf,
                                             const float* __restrict__ hc,
                                             float* __restrict__ hn,
                                             float* __restrict__ thout) {
  __shared__ float s_h[HH];
  const int blk = blockIdx.x, tid = threadIdx.x;
  const int b = blk >> 3, bb = blk & 7;
  const int lane = tid & 63, wv = tid >> 6;
#pragma unroll
  for (int q = 0; q < 4; ++q) {
    const int j = tid + q * 256;
    const int o = b * HH + j;
    const float gxr = gbuf[0 * (BB * HH) + o];
    const float gxz = gbuf[1 * (BB * HH) + o];
    const float gxn = gbuf[2 * (BB * HH) + o];
    const float ghr = gbuf[3 * (BB * HH) + o];
    const float ghz = gbuf[4 * (BB * HH) + o];
    const float ghn = gbuf[5 * (BB * HH) + o];
    const float rr = 1.f / (1.f + expf(-(gxr + ghr)));
    const float zz = 1.f / (1.f + expf(-(gxz + ghz)));
    const float nn = tanhf(gxn + rr * ghn);
    const float hv = (1.f - zz) * nn + zz * hc[o];
    s_h[j] = hv;
    if (bb == 0) hn[o] = hv;
  }
  __syncthreads();
  const float4* h4 = (const float4*)s_h;
  const int j0 = bb * 128 + wv * 32;
  for (int i = 0; i < 32; ++i) {
    const int j = j0 + i;
    const float4* wr = (const float4*)(W + (size_t)j * HH);
    float acc = 0.f;
#pragma unroll 4
    for (int k = lane; k < HH / 4; k += 64) acc += dot4(wr[k], h4[k]);
    acc = wave_reduce_sum(acc);
    if (lane == 0) thout[b * HH + j] = acc + bias[j];
  }
}

// ---------------- attention part 2 (round-1 verbatim, passing) ---------------------
__global__ __launch_bounds__(512) void k_attn2(const float* __restrict__ th,
                                               const float* __restrict__ enc,
                                               float* __restrict__ ctx) {
  __shared__ float s_th[HH];
  __shared__ float s_sc[SS];
  __shared__ float s_red[512];
  const int b = blockIdx.x, tid = threadIdx.x;
  const int lane = tid & 63, wv = tid >> 6;
  for (int i = tid; i < HH; i += 512) s_th[i] = th[b * HH + i];
  __syncthreads();
  const float4* th4 = (const float4*)s_th;
  for (int s = wv; s < SS; s += 8) {
    const float4* er = (const float4*)(enc + ((size_t)b * SS + s) * HH);
    float acc = 0.f;
#pragma unroll 4
    for (int k = lane; k < HH / 4; k += 64) acc += dot4(er[k], th4[k]);
    acc = wave_reduce_sum(acc);
    if (lane == 0) s_sc[s] = acc;
  }
  __syncthreads();
  const float v = (tid < SS) ? s_sc[tid] : -3.4e38f;
  s_red[tid] = v;
  __syncthreads();
  for (int o = 256; o; o >>= 1) {
    if (tid < o) s_red[tid] = fmaxf(s_red[tid], s_red[tid + o]);
    __syncthreads();
  }
  const float m = s_red[0];
  __syncthreads();
  const float e = (tid < SS) ? expf(v - m) : 0.f;
  s_red[tid] = e;
  __syncthreads();
  for (int o = 256; o; o >>= 1) {
    if (tid < o) s_red[tid] += s_red[tid + o];
    __syncthreads();
  }
  const float den = s_red[0];
  __syncthreads();
  if (tid < SS) s_sc[tid] = e / den;
  __syncthreads();
  if (tid < 256) {
    const float4* eb = (const float4*)(enc + (size_t)b * SS * HH);
    float4 acc = make_float4(0.f, 0.f, 0.f, 0.f);
    for (int s = 0; s < SS; ++s) {
      const float a = s_sc[s];
      const float4 x = eb[s * (HH / 4) + tid];
      acc.x += a * x.x; acc.y += a * x.y; acc.z += a * x.z; acc.w += a * x.w;
    }
    ((float4*)(ctx + b * HH))[tid] = acc;
  }
}

// ---------------- GRU chains (round-1 verbatim k_gru3, passing; FROZEN) ------------
__global__ __launch_bounds__(256) void k_gru3(const float* __restrict__ hc,
                                              const float* __restrict__ ctx,
                                              const float* __restrict__ sel,
                                              const float* __restrict__ embt,
                                              const int* __restrict__ samp,
                                              const float* __restrict__ Wih,
                                              const float* __restrict__ Whh,
                                              const float* __restrict__ bih,
                                              const float* __restrict__ bhh,
                                              float* __restrict__ gbuf) {
  __shared__ float s_x[32][130];
  const int blk = blockIdx.x, tid = threadIdx.x;
  const int lane = tid & 63, wv = tid >> 6;
  const int b = lane & 31, rp = lane >> 5;
  const int lb = tid >> 3, lg = tid & 7;
  const bool ih = blk < 384;
  const int base = (ih ? blk : blk - 384) * 8;
  const int row = base + 2 * wv + rp;  // 0..3071
  float acc = 0.f;
  int ei = 0;
  if (ih) {
    const int p = samp[lb];
    ei = (p > VV) ? 3 : p;       // strict >, as in source
    if (ei >= VV) ei = VV - 1;   // jnp OOB gather clamps
  }
  const int NCH = ih ? 18 : 8;
  for (int ch = 0; ch < NCH; ++ch) {
    const float* src;
    if (ih) {
      if (ch < 8) src = ctx + lb * HH + ch * 128;
      else if (ch < 16) src = sel + lb * HH + (ch - 8) * 128;
      else src = embt + (size_t)ei * EE + (ch - 16) * 128;
    } else {
      src = hc + lb * HH + ch * 128;
    }
    float2* drow = (float2*)&s_x[lb][0];
#pragma unroll
    for (int m = 0; m < 4; ++m) {
      const int col = lg + m * 8;
      const float4 v4 = ((const float4*)src)[col];
      drow[2 * col] = make_float2(v4.x, v4.y);
      drow[2 * col + 1] = make_float2(v4.z, v4.w);
    }
    __syncthreads();
    const float4* wr = ih ? (const float4*)(Wih + (size_t)row * GIN + ch * 128)
                          : (const float4*)(Whh + (size_t)row * HH + ch * 128);
    const float2* xr = (const float2*)&s_x[b][0];
#pragma unroll 8
    for (int kc = 0; kc < 32; ++kc) {
      const float2 xa = xr[2 * kc], xb2 = xr[2 * kc + 1];
      acc += dot4(wr[kc], make_float4(xa.x, xa.y, xb2.x, xb2.y));
    }
    __syncthreads();
  }
  if (ih) {
    acc += bih[row];
    gbuf[(size_t)(row >> 10) * (BB * HH) + b * HH + (row & 1023)] = acc;
  } else {
    acc += bhh[row];
    gbuf[(size_t)(3 + (row >> 10)) * (BB * HH) + b * HH + (row & 1023)] = acc;
  }
}

// ---------------- generate logits (round-1 verbatim k_gen3, passing; FROZEN) -------
__global__ __launch_bounds__(256) void k_gen3(const float* __restrict__ hn,
                                              const float* __restrict__ Wo,
                                              const float* __restrict__ bo,
                                              float* __restrict__ gen) {
  __shared__ float s_h[32][130];
  const int blk = blockIdx.x, tid = threadIdx.x;
  const int lane = tid & 63, wv = tid >> 6;
  const int b = lane & 31, rp = lane >> 5;
  const int lb = tid >> 3, lg = tid & 7;
  const int v0 = blk * 16;
  const int va = v0 + 2 * wv + rp;
  const int vb = va + 8;
  float acc0 = 0.f, acc1 = 0.f;
  for (int ch = 0; ch < 8; ++ch) {
    const float* src = hn + lb * HH + ch * 128;
    float2* drow = (float2*)&s_h[lb][0];
#pragma unroll
    for (int m = 0; m < 4; ++m) {
      const int col = lg + m * 8;
      const float4 v4 = ((const float4*)src)[col];
      drow[2 * col] = make_float2(v4.x, v4.y);
      drow[2 * col + 1] = make_float2(v4.z, v4.w);
    }
    __syncthreads();
    const float4* wr0 = (const float4*)(Wo + (size_t)va * HH + ch * 128);
    const float4* wr1 = (const float4*)(Wo + (size_t)vb * HH + ch * 128);
    const float2* xr = (const float2*)&s_h[b][0];
#pragma unroll 8
    for (int kc = 0; kc < 32; ++kc) {
      const float2 xa = xr[2 * kc], xb2 = xr[2 * kc + 1];
      const float4 xv = make_float4(xa.x, xa.y, xb2.x, xb2.y);
      acc0 += dot4(wr0[kc], xv);
      acc1 += dot4(wr1[kc], xv);
    }
    __syncthreads();
  }
  gen[(size_t)b * VV + va] = acc0 + bo[va];
  gen[(size_t)b * VV + vb] = acc1 + bo[vb];
}

// ---------------- fused copy2 + out, hash-table edition (round-5 verbatim) ---------
__global__ __launch_bounds__(1024) void k_fin(const float* __restrict__ th2,
                                              const float* __restrict__ enc,
                                              const int* __restrict__ inp,
                                              const float* __restrict__ gen,
                                              float* __restrict__ out,
                                              float* __restrict__ seln,
                                              int* __restrict__ samp,
                                              const int t) {
  __shared__ float s_th[HH];
  __shared__ float s_red[1024];
  __shared__ int s_idx[1024];
  __shared__ float s_sc[SS];
  __shared__ float s_norm[SS];
  __shared__ int hkey[512];
  __shared__ float hval[512];
  const int b = blockIdx.x, tid = threadIdx.x;
  const int lane = tid & 63, wv = tid >> 6;  // 16 waves
  // ---- part A: copy scores (bit-exact k_copy2 per-s math) + hash scatter ----
  for (int i = tid; i < HH; i += 1024) s_th[i] = th2[b * HH + i];
  if (tid < 512) { hkey[tid] = -1; hval[tid] = 0.f; }
  __syncthreads();
  const float4* th4 = (const float4*)s_th;
  for (int s = wv; s < SS; s += 16) {
    const float4* er = (const float4*)(enc + ((size_t)b * SS + s) * HH);
    float acc = 0.f;
#pragma unroll 4
    for (int k = lane; k < HH / 4; k += 64) acc += dot4(er[k], th4[k]);
    acc = wave_reduce_sum(acc);
    if (lane == 0) s_sc[s] = acc;
  }
  __syncthreads();
  if (tid < SS) {
    const int tok = inp[b * SS + tid];
    const float val = s_sc[tid];
    unsigned h = ((unsigned)tok * 2654435761u) >> 23;  // 9 bits -> 0..511
    while (true) {
      const int prev = atomicCAS(&hkey[h], -1, tok);
      if (prev == -1 || prev == tok) { atomicAdd(&hval[h], val); break; }
      h = (h + 1) & 511;
    }
  }
  __syncthreads();
  // ---- part B: softmax/log/argmax (register-cached logits) ----
  const float* gb = gen + (size_t)b * VV;
  float gr[16], cr[16];
  float m = -3.4e38f;
#pragma unroll
  for (int k = 0; k < 16; ++k) {
    const int v = tid + k * 1024;
    if (v < VV) {
      const float gv = (v == 0) ? NEGV : gb[v];
      float cv = NEGV;
      if (v != 0) {
        unsigned h = ((unsigned)v * 2654435761u) >> 23;
        while (true) {
          const int kk = hkey[h];
          if (kk == v) { cv = hval[h]; break; }
          if (kk == -1) break;
          h = (h + 1) & 511;
        }
      }
      gr[k] = gv; cr[k] = cv;
      m = fmaxf(m, fmaxf(gv, cv));
    }
  }
  s_red[tid] = m;
  __syncthreads();
  for (int o = 512; o; o >>= 1) {
    if (tid < o) s_red[tid] = fmaxf(s_red[tid], s_red[tid + o]);
    __syncthreads();
  }
  m = s_red[0];
  __syncthreads();
  float sm = 0.f;
#pragma unroll
  for (int k = 0; k < 16; ++k) {
    const int v = tid + k * 1024;
    if (v < VV) sm += expf(gr[k] - m) + expf(cr[k] - m);
  }
  s_red[tid] = sm;
  __syncthreads();
  for (int o = 512; o; o >>= 1) {
    if (tid < o) s_red[tid] += s_red[tid + o];
    __syncthreads();
  }
  const float inv = 1.f / s_red[0];
  __syncthreads();
  float bv = -3.4e38f;
  int bi = VSS;
  float* ob = out + ((size_t)t * BB + b) * VSS;
#pragma unroll
  for (int k = 0; k < 16; ++k) {
    const int v = tid + k * 1024;
    if (v < VV) {
      const float p = expf(gr[k] - m) * inv + expf(cr[k] - m) * inv;
      const float lp = logf(p + 1e-10f);
      ob[v] = lp;
      if (lp > bv) { bv = lp; bi = v; }
    }
  }
  const float lpz = logf(1e-10f);  // extended-vocab slots: prob exactly 0
  for (int j = VV + tid; j < VSS; j += 1024) ob[j] = lpz;
  s_red[tid] = bv;
  s_idx[tid] = bi;
  __syncthreads();
  for (int o = 512; o; o >>= 1) {
    if (tid < o) {
      const float ov = s_red[tid + o];
      const int oi = s_idx[tid + o];
      if (ov > s_red[tid] || (ov == s_red[tid] && oi < s_idx[tid])) {
        s_red[tid] = ov;
        s_idx[tid] = oi;
      }
    }
    __syncthreads();
  }
  const int sp = s_idx[0];
  if (tid == 0) {
    samp[b] = sp;
    out[(size_t)TT * BB * VSS + (size_t)b * TT + t] = (float)sp;
  }
  __syncthreads();
  // ---- selective read (cseq values = s_sc, identical) ----
  float sv = 0.f;
  if (tid < SS) sv = (inp[b * SS + tid] == sp) ? s_sc[tid] : 0.f;
  s_red[tid] = (tid < SS) ? fabsf(sv) : 0.f;
  __syncthreads();
  for (int o = 512; o; o >>= 1) {
    if (tid < o) s_red[tid] += s_red[tid + o];
    __syncthreads();
  }
  const float nf = 1.f / fmaxf(s_red[0], 1e-12f);
  __syncthreads();
  if (tid < SS) s_norm[tid] = sv * nf;
  __syncthreads();
  if (tid < 256) {
    const float4* eb = (const float4*)(enc + (size_t)b * SS * HH);
    float4 acc = make_float4(0.f, 0.f, 0.f, 0.f);
    for (int s = 0; s < SS; ++s) {
      const float a = s_norm[s];
      if (a != 0.f) {
        const float4 x = eb[s * (HH / 4) + tid];
        acc.x += a * x.x; acc.y += a * x.y; acc.z += a * x.z; acc.w += a * x.w;
      }
    }
    ((float4*)(seln + b * HH))[tid] = acc;
  }
}

extern "C" void kernel_launch(void* const* d_in, const int* in_sizes, int n_in,
                              void* d_out, int out_size, void* d_ws, size_t ws_size,
                              hipStream_t stream) {
  const int* inp = (const int*)d_in[0];
  const float* hidden = (const float*)d_in[1];
  const float* enc = (const float*)d_in[2];
  const float* Wa = (const float*)d_in[4];
  const float* ba = (const float*)d_in[5];
  const float* Wc = (const float*)d_in[6];
  const float* bc = (const float*)d_in[7];
  const float* emb = (const float*)d_in[8];
  const float* Wih = (const float*)d_in[9];
  const float* Whh = (const float*)d_in[10];
  const float* bih = (const float*)d_in[11];
  const float* bhh = (const float*)d_in[12];
  const float* Wo = (const float*)d_in[13];
  const float* bo = (const float*)d_in[14];
  float* out = (float*)d_out;

  float* ws = (float*)d_ws;
  float* hb0 = ws;                        // [B*H]
  float* hb1 = hb0 + BB * HH;             // [B*H]
  float* sb0 = hb1 + BB * HH;             // [B*H]
  float* sb1 = sb0 + BB * HH;             // [B*H]
  float* ctx = sb1 + BB * HH;             // [B*H]
  float* th = ctx + BB * HH;              // [B*H]
  float* th2 = th + BB * HH;              // [B*H]
  float* gbuf = th2 + BB * HH;            // [6*B*H]
  float* gen = gbuf + 6 * BB * HH;        // [B*V]
  int* samp = (int*)(gen + (size_t)BB * VV);  // [B]

  k_init<<<(BB * VSS + 255) / 256, 256, 0, stream>>>(out, sb0, samp);

  for (int t = 1; t < TT; ++t) {
    const float* hc = (t == 1) ? hidden : (((t - 1) & 1) ? hb0 : hb1);
    float* hw = (t & 1) ? hb0 : hb1;
    const float* sr = (t == 1) ? sb0 : (((t - 1) & 1) ? sb1 : sb0);
    float* sw = (t & 1) ? sb1 : sb0;

    k_th<<<BB * 8, 256, 0, stream>>>(Wa, ba, hc, th);
    k_attn2<<<BB, 512, 0, stream>>>(th, enc, ctx);
    k_gru3<<<768, 256, 0, stream>>>(hc, ctx, sr, emb, samp, Wih, Whh, bih, bhh,
                                    gbuf);
    k_thg<<<BB * 8, 256, 0, stream>>>(Wc, bc, gbuf, hc, hw, th2);
    k_gen3<<<VV / 16, 256, 0, stream>>>(hw, Wo, bo, gen);
    k_fin<<<BB, 1024, 0, stream>>>(th2, enc, inp, gen, out, sw, samp, t);
  }
}